// Round 2
// 831.123 us; speedup vs baseline: 1.0607x; 1.0607x over previous
//
#include <hip/hip_runtime.h>

// FeatureDecoder: 4x (Linear -> BN(batch stats) -> ReLU -> Linear) with gathers.
// R4: identical structure to R3 (256x256xBK64, 8-wave, 4-phase counted-vmcnt
// pipeline T3+T4, LDS XOR-swizzle T2, setprio T5), with raw s_barrier bracketed
// by compiler memory fences: __builtin_amdgcn_s_barrier() is NOT an LLVM memory
// fence, so C++ ds_reads placed after a barrier could legally be hoisted above
// it. The empty asm-with-memory-clobber pins LDS/global accesses to their side
// of each barrier at zero instruction cost.

typedef unsigned short u16;
typedef __attribute__((ext_vector_type(8))) short bf16x8;
typedef __attribute__((ext_vector_type(4))) float f32x4;

#define UNROLL _Pragma("unroll")
#define EPW 264  // epilogue LDS row stride (u16)

__device__ __forceinline__ float b2f(u16 u) {
    union { unsigned int i; float f; } v; v.i = ((unsigned int)u) << 16; return v.f;
}
__device__ __forceinline__ u16 f2b(float f) {
    union { float f; unsigned int i; } v; v.f = f;
    unsigned int r = v.i + 0x7FFFu + ((v.i >> 16) & 1u);
    return (u16)(r >> 16);
}

__device__ __forceinline__ void gld_lds16(const u16* g, u16* l) {
    __builtin_amdgcn_global_load_lds(
        (const __attribute__((address_space(1))) unsigned int*)g,
        (__attribute__((address_space(3))) unsigned int*)l,
        16, 0, 0);
}

#define VMCNT(n) asm volatile("s_waitcnt vmcnt(" #n ")" ::: "memory")
#define LGKM0    asm volatile("s_waitcnt lgkmcnt(0)" ::: "memory")
#define BAR()    do{ asm volatile("" ::: "memory"); \
                     __builtin_amdgcn_s_barrier(); \
                     asm volatile("" ::: "memory"); }while(0)

union SMem {
    // staging: 2 buffers x (A 256x64 + B 256x64) bf16 = 128 KB; ss: scale|shift
    struct { u16 a[2][256 * 64]; u16 b[2][256 * 64]; float ss[2048]; } st;
    u16 ep[256 * EPW];  // 135168 B epilogue overlay (st dead by then)
};

// ---------------- GEMM: C(MxN) = A(MxK bf16) @ BT(NxK bf16)^T ----------------
template <bool AFFINE_A, bool STATS, bool OUT_F32, bool GATHER>
__global__ __launch_bounds__(512, 2) void gemm_bn(
    const u16* __restrict__ A, const u16* __restrict__ BT, void* __restrict__ Cout,
    const float* __restrict__ scale, const float* __restrict__ shift,
    const float* __restrict__ bias,
    float* __restrict__ psum, float* __restrict__ psumsq,
    const u16* __restrict__ Xg, const int* __restrict__ pool,
    int nfShift, int Nc, int Chalf,
    int N, int K)
{
    __shared__ __align__(16) SMem sm;

    const int tid  = threadIdx.x;
    const int w    = tid >> 6;
    const int lane = tid & 63;
    const int wm   = w >> 2, wn = w & 3;      // 2M x 4N waves; per-wave C = 128x64
    const int l15  = lane & 15;
    const int xorv = (lane & 7) << 3;          // read-side swizzle (row&7 == lane&7)
    const int swz8 = ((lane & 7) ^ (lane >> 3)) << 3;  // write-source swizzle chunk
    const int kS0  = (((lane >> 4) << 3)) ^ xorv;
    const int kS1  = (32 + ((lane >> 4) << 3)) ^ xorv;

    // XCD-aware bijective swizzle (all grids are %8==0): contiguous chunk per XCD.
    int bm, bn;
    {
        const int nbn  = (int)gridDim.x;
        const int nwg  = nbn * (int)gridDim.y;
        const int flat = (int)(blockIdx.y * gridDim.x + blockIdx.x);
        const int wg   = (flat & 7) * (nwg >> 3) + (flat >> 3);
        const int lb   = 31 - __builtin_clz(nbn);
        bn = wg & (nbn - 1);
        bm = wg >> lb;
    }

    // ---- staging source/dest setup ----
    // A units: u=0 -> tile rows 0-63 & 128-191 (qi=0 needs), u=1 -> 64-127 & 192-255
    // B units: u=qj=0 -> rows {wnblk+0..31}, u=1 -> {wnblk+32..63}
    const u16* aS[2][2]; const u16* xS[2][2]; const u16* bS[2][2];
    int dA[2][2], dB[2][2], wIdx[2][2];
    UNROLL for (int u = 0; u < 2; u++)
    UNROLL for (int ld = 0; ld < 2; ld++) {
        const int urb = w * 16 + ld * 8;          // wave-uniform 8-row chunk base
        const int ur  = urb + (lane >> 3);        // per-lane unit-row
        {
            const int trb = urb + (urb >= 64 ? 64 : 0) + u * 64;
            const int tr  = ur  + (ur  >= 64 ? 64 : 0) + u * 64;
            dA[u][ld] = trb * 64;
            const int rowG = bm * 256 + tr;
            if constexpr (GATHER) {
                const int b = rowG >> nfShift;
                const int p = pool[rowG];
                aS[u][ld] = A  + (size_t)rowG * Chalf + swz8;
                xS[u][ld] = Xg + ((size_t)b * Nc + p) * Chalf + swz8;
            } else if constexpr (AFFINE_A) {
                aS[u][ld] = A + (size_t)rowG * K + ((lane & 7) << 3);  // linear src
                wIdx[u][ld] = tr * 64 + swz8;                          // swizzled dst
            } else {
                aS[u][ld] = A + (size_t)rowG * K + swz8;
            }
        }
        {
            const int trb = ((urb >> 5) << 6) + (urb & 31) + u * 32;
            const int tr  = ((ur  >> 5) << 6) + (ur  & 31) + u * 32;
            dB[u][ld] = trb * 64;
            bS[u][ld] = BT + (size_t)(bn * 256 + tr) * K + swz8;
        }
    }

    f32x4 acc[8][4];
    const f32x4 zero = {0.f, 0.f, 0.f, 0.f};
    UNROLL for (int i = 0; i < 8; i++)
    UNROLL for (int j = 0; j < 4; j++) acc[i][j] = zero;
    bf16x8 afr[4][2];
    bf16x8 bfr[2][2][2];
    uint4 rA[2][2];  // AFFINE in-flight A regs (dead code otherwise)

#define STAGE_A_(u, nb, KOF) do{ \
    if constexpr (AFFINE_A) { \
        rA[u][0] = *(const uint4*)(aS[u][0] + (KOF)); \
        rA[u][1] = *(const uint4*)(aS[u][1] + (KOF)); \
    } else if constexpr (GATHER) { \
        const u16 *s0_, *s1_; \
        if ((KOF) < Chalf) { s0_ = aS[u][0] + (KOF); s1_ = aS[u][1] + (KOF); } \
        else { s0_ = xS[u][0] + ((KOF) - Chalf); s1_ = xS[u][1] + ((KOF) - Chalf); } \
        gld_lds16(s0_, &sm.st.a[(nb)][dA[u][0]]); \
        gld_lds16(s1_, &sm.st.a[(nb)][dA[u][1]]); \
    } else { \
        gld_lds16(aS[u][0] + (KOF), &sm.st.a[(nb)][dA[u][0]]); \
        gld_lds16(aS[u][1] + (KOF), &sm.st.a[(nb)][dA[u][1]]); \
    } }while(0)

#define STAGE_B_(u, nb, KOF) do{ \
    gld_lds16(bS[u][0] + (KOF), &sm.st.b[(nb)][dB[u][0]]); \
    gld_lds16(bS[u][1] + (KOF), &sm.st.b[(nb)][dB[u][1]]); }while(0)

#define AFF_WRITE_(u, tb, KOF) do{ if constexpr (AFFINE_A) { \
    const int kb_ = (KOF) + ((lane & 7) << 3); \
    const float4 sc0_ = *(const float4*)&sm.st.ss[kb_]; \
    const float4 sc1_ = *(const float4*)&sm.st.ss[kb_ + 4]; \
    const float4 sh0_ = *(const float4*)&sm.st.ss[1024 + kb_]; \
    const float4 sh1_ = *(const float4*)&sm.st.ss[1024 + kb_ + 4]; \
    UNROLL for (int ld_ = 0; ld_ < 2; ld_++) { \
        union { uint4 u4; u16 s[8]; } r_, o_; r_.u4 = rA[u][ld_]; \
        o_.s[0] = f2b(fmaxf(b2f(r_.s[0]) * sc0_.x + sh0_.x, 0.f)); \
        o_.s[1] = f2b(fmaxf(b2f(r_.s[1]) * sc0_.y + sh0_.y, 0.f)); \
        o_.s[2] = f2b(fmaxf(b2f(r_.s[2]) * sc0_.z + sh0_.z, 0.f)); \
        o_.s[3] = f2b(fmaxf(b2f(r_.s[3]) * sc0_.w + sh0_.w, 0.f)); \
        o_.s[4] = f2b(fmaxf(b2f(r_.s[4]) * sc1_.x + sh1_.x, 0.f)); \
        o_.s[5] = f2b(fmaxf(b2f(r_.s[5]) * sc1_.y + sh1_.y, 0.f)); \
        o_.s[6] = f2b(fmaxf(b2f(r_.s[6]) * sc1_.z + sh1_.z, 0.f)); \
        o_.s[7] = f2b(fmaxf(b2f(r_.s[7]) * sc1_.w + sh1_.w, 0.f)); \
        *(uint4*)&sm.st.a[(tb)][wIdx[u][ld_]] = o_.u4; } \
    LGKM0; } }while(0)

#define READ_A(buf, qi) do{ const u16* p_ = sm.st.a[(buf)]; \
    UNROLL for (int i_ = 0; i_ < 4; i_++) { \
        const int rb_ = (wm * 128 + ((qi) * 4 + i_) * 16 + l15) * 64; \
        afr[i_][0] = *(const bf16x8*)&p_[rb_ + kS0]; \
        afr[i_][1] = *(const bf16x8*)&p_[rb_ + kS1]; } }while(0)

#define READ_B(buf, qj) do{ const u16* p_ = sm.st.b[(buf)]; \
    UNROLL for (int j_ = 0; j_ < 2; j_++) { \
        const int rb_ = (wn * 64 + ((qj) * 2 + j_) * 16 + l15) * 64; \
        bfr[qj][j_][0] = *(const bf16x8*)&p_[rb_ + kS0]; \
        bfr[qj][j_][1] = *(const bf16x8*)&p_[rb_ + kS1]; } }while(0)

#define MFMA_Q(qi, qj) do{ __builtin_amdgcn_s_setprio(1); \
    UNROLL for (int i_ = 0; i_ < 4; i_++) \
    UNROLL for (int j_ = 0; j_ < 2; j_++) { \
        acc[(qi)*4+i_][(qj)*2+j_] = __builtin_amdgcn_mfma_f32_16x16x32_bf16( \
            afr[i_][0], bfr[qj][j_][0], acc[(qi)*4+i_][(qj)*2+j_], 0, 0, 0); \
        acc[(qi)*4+i_][(qj)*2+j_] = __builtin_amdgcn_mfma_f32_16x16x32_bf16( \
            afr[i_][1], bfr[qj][j_][1], acc[(qi)*4+i_][(qj)*2+j_], 0, 0, 0); } \
    __builtin_amdgcn_s_setprio(0); }while(0)

    const int nkt = K >> 6;

    // ---- prologue: tile 0 fully staged, full drain (loop waits stay valid) ----
    if constexpr (AFFINE_A) {
        for (int i = tid; i < K; i += 512) {
            sm.st.ss[i] = scale[i]; sm.st.ss[1024 + i] = shift[i];
        }
    }
    STAGE_A_(0, 0, 0); STAGE_B_(0, 0, 0); STAGE_B_(1, 0, 0); STAGE_A_(1, 0, 0);
    asm volatile("s_waitcnt vmcnt(0) lgkmcnt(0)" ::: "memory");
    BAR();
    if constexpr (AFFINE_A) { AFF_WRITE_(0, 0, 0); BAR(); }

    // ---- main loop: iteration t computes tile t, stages tile t+1 ----
    for (int t = 0; t < nkt - 1; ++t) {
        const int buf = t & 1, nb = buf ^ 1;
        const int kofN = (t + 1) << 6;
        // PH0: Q(0,0)
        STAGE_A_(0, nb, kofN);
        READ_A(buf, 0);
        READ_B(buf, 0);
        BAR();
        MFMA_Q(0, 0);
        // PH1: Q(0,1)  (confirm B1(t): oldest 2 of 8)
        STAGE_B_(0, nb, kofN);
        VMCNT(6);
        BAR();
        READ_B(buf, 1);
        MFMA_Q(0, 1);
        // PH2: Q(1,1)  (confirm A1(t))
        STAGE_B_(1, nb, kofN);
        VMCNT(6);
        AFF_WRITE_(1, buf, t << 6);   // AFFINE: A-hi of tile t (regs from t-1.PH3)
        BAR();
        READ_A(buf, 1);
        MFMA_Q(1, 1);
        // PH3: Q(1,0)  (regs only)
        STAGE_A_(1, nb, kofN);
        BAR();
        MFMA_Q(1, 0);
        // END: confirm A0,B0(t+1); leave B1,A1(t+1) in flight
        VMCNT(4);
        AFF_WRITE_(0, nb, kofN);      // AFFINE: A-lo of tile t+1
        BAR();
    }

    // ---- peeled last tile: no staging, tighter waits ----
    {
        const int t = nkt - 1, buf = t & 1;
        READ_A(buf, 0);
        READ_B(buf, 0);
        BAR();
        MFMA_Q(0, 0);
        VMCNT(2);
        BAR();
        READ_B(buf, 1);
        MFMA_Q(0, 1);
        VMCNT(0);
        AFF_WRITE_(1, buf, t << 6);
        BAR();
        READ_A(buf, 1);
        MFMA_Q(1, 1);
        BAR();
        MFMA_Q(1, 0);
    }

    // ---- epilogue: C/D layout col=lane&15, row=(lane>>4)*4+reg ----
    const int cl = l15, quad = lane >> 4;
    if constexpr (OUT_F32) {
        UNROLL for (int j = 0; j < 4; j++) {
            const int col = bn * 256 + wn * 64 + j * 16 + cl;
            const float bcol = bias[col];
            UNROLL for (int i = 0; i < 8; i++) {
                const int r0 = bm * 256 + wm * 128 + i * 16 + quad * 4;
                UNROLL for (int r = 0; r < 4; r++)
                    ((float*)Cout)[(size_t)(r0 + r) * N + col] = acc[i][j][r] + bcol;
            }
        }
    } else {
        UNROLL for (int j = 0; j < 4; j++) {
            const int colL = wn * 64 + j * 16 + cl;
            const int col = bn * 256 + colL;
            float bcol = 0.f;
            if constexpr (!STATS) bcol = bias[col];
            float s = 0.f, ss2 = 0.f;
            UNROLL for (int i = 0; i < 8; i++) {
                const int rL0 = wm * 128 + i * 16 + quad * 4;
                UNROLL for (int r = 0; r < 4; r++) {
                    const float v = acc[i][j][r];
                    if constexpr (STATS) { s += v; ss2 += v * v; }
                    sm.ep[(rL0 + r) * EPW + colL] = f2b(v + bcol);
                }
            }
            if constexpr (STATS) {
                s   += __shfl_xor(s, 16);   s   += __shfl_xor(s, 32);
                ss2 += __shfl_xor(ss2, 16); ss2 += __shfl_xor(ss2, 32);
                if (quad == 0) { atomicAdd(&psum[col], s); atomicAdd(&psumsq[col], ss2); }
            }
        }
        __syncthreads();
        u16* Cb = (u16*)Cout;
        UNROLL for (int it = 0; it < 16; it++) {
            const int row = it * 16 + (tid >> 5);
            const int c8  = (tid & 31) * 8;
            const uint4 v = *(const uint4*)&sm.ep[row * EPW + c8];
            *(uint4*)(Cb + (size_t)(bm * 256 + row) * N + bn * 256 + c8) = v;
        }
    }
#undef STAGE_A_
#undef STAGE_B_
#undef AFF_WRITE_
#undef READ_A
#undef READ_B
#undef MFMA_Q
}

// ---------------- W (KxN fp32) -> WT (NxK bf16), tiled transpose ----------------
__global__ void cvt_transpose_w(const float* __restrict__ W, u16* __restrict__ WT, int K, int N) {
    __shared__ float t[32][33];
    const int tx = threadIdx.x, ty = threadIdx.y;
    const int n0 = blockIdx.x * 32, k0 = blockIdx.y * 32;
#pragma unroll
    for (int r = 0; r < 4; r++)
        t[ty + r * 8][tx] = W[(size_t)(k0 + ty + r * 8) * N + n0 + tx];
    __syncthreads();
#pragma unroll
    for (int r = 0; r < 4; r++)
        WT[(size_t)(n0 + ty + r * 8) * K + k0 + tx] = f2b(t[tx][ty + r * 8]);
}

// ---------------- fp32 -> bf16 elementwise (8 elems/thread) ----------------
__global__ void cvt_f32_bf16(const float* __restrict__ x, u16* __restrict__ y, long n8) {
    const long t = (long)blockIdx.x * 256 + threadIdx.x;
    if (t >= n8) return;
    const float4 a = ((const float4*)x)[t * 2];
    const float4 b = ((const float4*)x)[t * 2 + 1];
    union { uint4 u; u16 s[8]; } o;
    o.s[0] = f2b(a.x); o.s[1] = f2b(a.y); o.s[2] = f2b(a.z); o.s[3] = f2b(a.w);
    o.s[4] = f2b(b.x); o.s[5] = f2b(b.y); o.s[6] = f2b(b.z); o.s[7] = f2b(b.w);
    ((uint4*)y)[t] = o.u;
}

// ---------------- per-channel BN scale/shift from sums ----------------
__global__ void bn_finalize(const float* __restrict__ sum, const float* __restrict__ sumsq,
                            const float* __restrict__ g, const float* __restrict__ be,
                            float* __restrict__ scale, float* __restrict__ shift,
                            int Cc, float invM) {
    const int c = blockIdx.x * 256 + threadIdx.x;
    if (c >= Cc) return;
    const float mu = sum[c] * invM;
    const float var = fmaf(sumsq[c], invM, -mu * mu);
    const float sc = g[c] * rsqrtf(var + 1e-5f);
    scale[c] = sc;
    shift[c] = fmaf(-mu, sc, be[c]);
}

extern "C" void kernel_launch(void* const* d_in, const int* in_sizes, int n_in,
                              void* d_out, int out_size, void* d_ws, size_t ws_size,
                              hipStream_t stream) {
    const float* f0     = (const float*)d_in[0];
    const float* f1     = (const float*)d_in[1];
    const float* f2     = (const float*)d_in[2];
    const float* up0_w1 = (const float*)d_in[3];
    const float* up0_g  = (const float*)d_in[5];
    const float* up0_be = (const float*)d_in[6];
    const float* up0_w2 = (const float*)d_in[7];
    const float* up0_b2 = (const float*)d_in[8];
    const float* up1_w1 = (const float*)d_in[9];
    const float* up1_g  = (const float*)d_in[11];
    const float* up1_be = (const float*)d_in[12];
    const float* up1_w2 = (const float*)d_in[13];
    const float* up1_b2 = (const float*)d_in[14];
    const float* sk0_w1 = (const float*)d_in[15];
    const float* sk0_g  = (const float*)d_in[17];
    const float* sk0_be = (const float*)d_in[18];
    const float* sk0_w2 = (const float*)d_in[19];
    const float* sk0_b2 = (const float*)d_in[20];
    const float* sk1_w1 = (const float*)d_in[21];
    const float* sk1_g  = (const float*)d_in[23];
    const float* sk1_be = (const float*)d_in[24];
    const float* sk1_w2 = (const float*)d_in[25];
    const float* sk1_b2 = (const float*)d_in[26];
    const int* pool0    = (const int*)d_in[27];
    const int* pool1    = (const int*)d_in[28];
    float* out = (float*)d_out;

    char* ws = (char*)d_ws;
    size_t off = 0;
    auto alloc = [&](size_t bytes) -> void* {
        void* p = ws + off;
        off += (bytes + 255) & ~(size_t)255;
        return p;
    };
    u16* w_up1_1 = (u16*)alloc((size_t)1024 * 1024 * 2);
    u16* w_up1_2 = (u16*)alloc((size_t)512 * 1024 * 2);
    u16* w_sk1_1 = (u16*)alloc((size_t)1024 * 1024 * 2);
    u16* w_sk1_2 = (u16*)alloc((size_t)512 * 1024 * 2);
    u16* w_up0_1 = (u16*)alloc((size_t)512 * 512 * 2);
    u16* w_up0_2 = (u16*)alloc((size_t)256 * 512 * 2);
    u16* w_sk0_1 = (u16*)alloc((size_t)512 * 512 * 2);
    u16* w_sk0_2 = (u16*)alloc((size_t)256 * 512 * 2);
    float* stats = (float*)alloc((size_t)4 * 4096 * 4);    // per MLP: sum|sumsq|scale|shift
    u16* Hbuf    = (u16*)alloc((size_t)131072 * 512 * 2);  // 134 MB
    u16* Xbuf    = (u16*)alloc((size_t)32768 * 512 * 2);   // 33 MB
    u16* f0b     = (u16*)alloc((size_t)4 * 32768 * 256 * 2); // 67 MB
    u16* f1b     = (u16*)alloc((size_t)4 * 8192 * 512 * 2);  // 33 MB
    u16* f2b_    = (u16*)alloc((size_t)4 * 2048 * 1024 * 2); // 17 MB

    const dim3 tb(32, 8);
    cvt_transpose_w<<<dim3(32, 32), tb, 0, stream>>>(up1_w1, w_up1_1, 1024, 1024);
    cvt_transpose_w<<<dim3(16, 32), tb, 0, stream>>>(up1_w2, w_up1_2, 1024, 512);
    cvt_transpose_w<<<dim3(32, 32), tb, 0, stream>>>(sk1_w1, w_sk1_1, 1024, 1024);
    cvt_transpose_w<<<dim3(16, 32), tb, 0, stream>>>(sk1_w2, w_sk1_2, 1024, 512);
    cvt_transpose_w<<<dim3(16, 16), tb, 0, stream>>>(up0_w1, w_up0_1, 512, 512);
    cvt_transpose_w<<<dim3(8, 16),  tb, 0, stream>>>(up0_w2, w_up0_2, 512, 256);
    cvt_transpose_w<<<dim3(16, 16), tb, 0, stream>>>(sk0_w1, w_sk0_1, 512, 512);
    cvt_transpose_w<<<dim3(8, 16),  tb, 0, stream>>>(sk0_w2, w_sk0_2, 512, 256);

    hipMemsetAsync(stats, 0, (size_t)4 * 4096 * sizeof(float), stream);
    cvt_f32_bf16<<<4096,  256, 0, stream>>>(f2, f2b_, 8388608L / 8);
    cvt_f32_bf16<<<8192,  256, 0, stream>>>(f1, f1b, 16777216L / 8);
    cvt_f32_bf16<<<16384, 256, 0, stream>>>(f0, f0b, 33554432L / 8);

    float* st0 = stats;
    float* st1 = stats + 4096;
    float* st2 = stats + 8192;
    float* st3 = stats + 12288;

    // ---- up1: (8192x1024)@(1024x1024) -> BN -> ReLU -> @(1024x512) ----
    gemm_bn<false, true, false, false><<<dim3(4, 32), 512, 0, stream>>>(
        f2b_, w_up1_1, Hbuf, nullptr, nullptr, nullptr, st0, st0 + 1024,
        nullptr, nullptr, 0, 0, 0, 1024, 1024);
    bn_finalize<<<4, 256, 0, stream>>>(st0, st0 + 1024, up1_g, up1_be, st0 + 2048, st0 + 3072, 1024, 1.f / 8192.f);
    gemm_bn<true, false, false, false><<<dim3(2, 32), 512, 0, stream>>>(
        Hbuf, w_up1_2, Xbuf, st0 + 2048, st0 + 3072, up1_b2, nullptr, nullptr,
        nullptr, nullptr, 0, 0, 0, 512, 1024);

    // ---- skip1: concat[f1|gather(X,pool1)] (32768x1024) @ w -> BN -> ReLU -> @ w2 ----
    gemm_bn<false, true, false, true><<<dim3(4, 128), 512, 0, stream>>>(
        f1b, w_sk1_1, Hbuf, nullptr, nullptr, nullptr, st1, st1 + 1024,
        Xbuf, pool1, 13, 2048, 512, 1024, 1024);
    bn_finalize<<<4, 256, 0, stream>>>(st1, st1 + 1024, sk1_g, sk1_be, st1 + 2048, st1 + 3072, 1024, 1.f / 32768.f);
    gemm_bn<true, false, false, false><<<dim3(2, 128), 512, 0, stream>>>(
        Hbuf, w_sk1_2, Xbuf, st1 + 2048, st1 + 3072, sk1_b2, nullptr, nullptr,
        nullptr, nullptr, 0, 0, 0, 512, 1024);

    // ---- up0: (32768x512)@(512x512) -> BN -> ReLU -> @(512x256) ----
    gemm_bn<false, true, false, false><<<dim3(2, 128), 512, 0, stream>>>(
        Xbuf, w_up0_1, Hbuf, nullptr, nullptr, nullptr, st2, st2 + 1024,
        nullptr, nullptr, 0, 0, 0, 512, 512);
    bn_finalize<<<2, 256, 0, stream>>>(st2, st2 + 1024, up0_g, up0_be, st2 + 2048, st2 + 3072, 512, 1.f / 32768.f);
    gemm_bn<true, false, false, false><<<dim3(1, 128), 512, 0, stream>>>(
        Hbuf, w_up0_2, Xbuf, st2 + 2048, st2 + 3072, up0_b2, nullptr, nullptr,
        nullptr, nullptr, 0, 0, 0, 256, 512);

    // ---- skip0: concat[f0|gather(X,pool0)] (131072x512) @ w -> BN -> ReLU -> @ w2 -> fp32 ----
    gemm_bn<false, true, false, true><<<dim3(2, 512), 512, 0, stream>>>(
        f0b, w_sk0_1, Hbuf, nullptr, nullptr, nullptr, st3, st3 + 1024,
        Xbuf, pool0, 15, 8192, 256, 512, 512);
    bn_finalize<<<2, 256, 0, stream>>>(st3, st3 + 1024, sk0_g, sk0_be, st3 + 2048, st3 + 3072, 512, 1.f / 131072.f);
    gemm_bn<true, false, true, false><<<dim3(1, 512), 512, 0, stream>>>(
        Hbuf, w_sk0_2, out, st3 + 2048, st3 + 3072, sk0_b2, nullptr, nullptr,
        nullptr, nullptr, 0, 0, 0, 256, 512);
}